// Round 4
// baseline (429.520 us; speedup 1.0000x reference)
//
#include <hip/hip_runtime.h>
#include <cstddef>
#include <cstdint>

#define TS 2048   // sequence length S
#define TD 512    // model dim D
#define TH 8      // heads
#define TDH 64    // head dim
#define CAP 128   // candidate entries per row (z > zmax-1); dense fallback beyond

typedef float f32x4 __attribute__((ext_vector_type(4)));
typedef short short8v __attribute__((ext_vector_type(8)));

struct us4 { unsigned short a, b, c, d; };

__device__ __forceinline__ unsigned short f2bf(float f) {
  unsigned u = __builtin_bit_cast(unsigned, f);
  u += 0x7fff + ((u >> 16) & 1);          // RNE
  return (unsigned short)(u >> 16);
}

// ---------------------------------------------------------------------------
// GEMM: C[M,N] = A[M,K] @ W[K,N] + bias[N].
// mode 0: f32 row-major to C. mode 1: bf16 head-major [b,h,s,dh] to outBf.
// ---------------------------------------------------------------------------
__global__ __launch_bounds__(256) void gemm_bias(
    const float* __restrict__ A, const float* __restrict__ W,
    const float* __restrict__ bias, float* __restrict__ C,
    short* __restrict__ outBf, int mode,
    int M, int N, int Kd)
{
  __shared__ float As[16][68];
  __shared__ float Bs[16][68];

  const int tid = threadIdx.x;
  const int tx = tid & 15;
  const int ty = tid >> 4;
  const int rowBase = blockIdx.x * 64;
  const int colBase = blockIdx.y * 64;

  const int ar = tid >> 2;
  const int ac = (tid & 3) << 2;
  const int brk = tid >> 4;
  const int bc  = (tid & 15) << 2;

  float acc[4][4] = {};

  for (int kt = 0; kt < Kd; kt += 16) {
    float4 av = *(const float4*)&A[(size_t)(rowBase + ar) * Kd + kt + ac];
    float4 bv = *(const float4*)&W[(size_t)(kt + brk) * N + colBase + bc];
    As[ac + 0][ar] = av.x;
    As[ac + 1][ar] = av.y;
    As[ac + 2][ar] = av.z;
    As[ac + 3][ar] = av.w;
    *(float4*)&Bs[brk][bc] = bv;
    __syncthreads();
#pragma unroll
    for (int k = 0; k < 16; ++k) {
      float4 a = *(const float4*)&As[k][ty << 2];
      float4 b = *(const float4*)&Bs[k][tx << 2];
      acc[0][0] += a.x * b.x; acc[0][1] += a.x * b.y; acc[0][2] += a.x * b.z; acc[0][3] += a.x * b.w;
      acc[1][0] += a.y * b.x; acc[1][1] += a.y * b.y; acc[1][2] += a.y * b.z; acc[1][3] += a.y * b.w;
      acc[2][0] += a.z * b.x; acc[2][1] += a.z * b.y; acc[2][2] += a.z * b.z; acc[2][3] += a.z * b.w;
      acc[3][0] += a.w * b.x; acc[3][1] += a.w * b.y; acc[3][2] += a.w * b.z; acc[3][3] += a.w * b.w;
    }
    __syncthreads();
  }

  float4 bb = *(const float4*)&bias[colBase + (tx << 2)];
  if (mode == 0) {
#pragma unroll
    for (int i = 0; i < 4; ++i) {
      float4 o;
      o.x = acc[i][0] + bb.x;
      o.y = acc[i][1] + bb.y;
      o.z = acc[i][2] + bb.z;
      o.w = acc[i][3] + bb.w;
      *(float4*)&C[(size_t)(rowBase + (ty << 2) + i) * N + colBase + (tx << 2)] = o;
    }
  } else {
#pragma unroll
    for (int i = 0; i < 4; ++i) {
      const int row = rowBase + (ty << 2) + i;
      const int col = colBase + (tx << 2);
      const int bI = row >> 11, s = row & 2047;
      const int hI = col >> 6, dh = col & 63;
      us4 o;
      o.a = f2bf(acc[i][0] + bb.x);
      o.b = f2bf(acc[i][1] + bb.y);
      o.c = f2bf(acc[i][2] + bb.z);
      o.d = f2bf(acc[i][3] + bb.w);
      *(us4*)(outBf + (((size_t)(bI * TH + hI) * TS + s) * TDH + dh)) = o;
    }
  }
}

// ---------------------------------------------------------------------------
// Fused attention, candidate-compaction version.
// Block = (16 q-rows, pair), 256 threads = 4 waves. Wave w owns 512 cols.
// MFMA C/D: col = lane&15, row = (lane>>4)*4 + reg.
// Phase A: QK^T (Z in regs). B: row max -> tau0 = zmax-1. C: compact
// candidates (z > tau0, superset of support) to LDS lists. D: per-16-lane-
// group Michelot on the list (no barriers). E: lane-parallel avg scatter +
// PV from the list. F: dense fallback for rows whose list overflowed.
// ---------------------------------------------------------------------------
__global__ __launch_bounds__(256) void fused_attn(
    const short* __restrict__ Qh, const short* __restrict__ Kh,
    const float* __restrict__ V, float* __restrict__ heads,
    float* __restrict__ avg)
{
  __shared__ int   idxS[16][CAP];          // candidate cols
  __shared__ float valS[16][CAP];          // candidate z values
  __shared__ float redMax[4][16];          // per-wave row maxima
  __shared__ float redA[4], redB[4], redMx[4];  // fallback reductions
  __shared__ int   cntS[16];
  __shared__ float tauS[16];

  const int tid  = threadIdx.x;
  const int w    = tid >> 6;
  const int lane = tid & 63;
  const int g    = lane >> 4;
  const int lc16 = lane & 15;
  const int pair = blockIdx.y;
  const int b    = pair >> 3;
  const int h    = pair & 7;
  const int q0   = blockIdx.x * 16;
  const int wcol0 = w * 512;

  const short* Qbase = Qh + ((size_t)pair * TS + q0) * TDH;
  short8v aq0 = *(const short8v*)(Qbase + lc16 * TDH + g * 8);
  short8v aq1 = *(const short8v*)(Qbase + lc16 * TDH + 32 + g * 8);

  const short* Kb = Kh + (size_t)pair * TS * TDH;
  const float* Vb = V + (size_t)b * TS * TDH;

  if (tid < 16) cntS[tid] = 0;

  // ---- A: QK^T ----
  f32x4 acc[32];
#pragma unroll
  for (int t = 0; t < 32; ++t) acc[t] = (f32x4){0.f, 0.f, 0.f, 0.f};
#pragma unroll
  for (int t = 0; t < 32; ++t) {
    const short* kp = Kb + (size_t)(wcol0 + t * 16 + lc16) * TDH + g * 8;
    short8v b0 = *(const short8v*)(kp);
    short8v b1 = *(const short8v*)(kp + 32);
    acc[t] = __builtin_amdgcn_mfma_f32_16x16x32_bf16(aq0, b0, acc[t], 0, 0, 0);
    acc[t] = __builtin_amdgcn_mfma_f32_16x16x32_bf16(aq1, b1, acc[t], 0, 0, 0);
  }

  // ---- B: row max ----
  float pmax[4];
#pragma unroll
  for (int i = 0; i < 4; ++i) pmax[i] = -1e30f;
#pragma unroll
  for (int t = 0; t < 32; ++t)
#pragma unroll
    for (int i = 0; i < 4; ++i) pmax[i] = fmaxf(pmax[i], acc[t][i]);
#pragma unroll
  for (int m = 1; m < 16; m <<= 1)
#pragma unroll
    for (int i = 0; i < 4; ++i) pmax[i] = fmaxf(pmax[i], __shfl_xor(pmax[i], m));
  if (lc16 == 0)
#pragma unroll
    for (int i = 0; i < 4; ++i) redMax[w][g * 4 + i] = pmax[i];
  __syncthreads();

  // tau0 for this lane's 4 rows (g*4+i)
  float tau0[4];
#pragma unroll
  for (int i = 0; i < 4; ++i) {
    const int r = g * 4 + i;
    tau0[i] = fmaxf(fmaxf(redMax[0][r], redMax[1][r]),
                    fmaxf(redMax[2][r], redMax[3][r])) - 1.0f;
  }

  // ---- C: compact candidates ----
#pragma unroll
  for (int t = 0; t < 32; ++t)
#pragma unroll
    for (int i = 0; i < 4; ++i) {
      const float v = acc[t][i];
      if (v > tau0[i]) {
        const int row = g * 4 + i;
        const int pos = atomicAdd(&cntS[row], 1);
        if (pos < CAP) { idxS[row][pos] = wcol0 + t * 16 + lc16; valS[row][pos] = v; }
      }
    }
  __syncthreads();

  // ---- D: per-group Michelot on row rw = w*4 + g (16 lanes, no barriers) ----
  {
    const int rw = w * 4 + g;
    const int cnt = cntS[rw];
    float tau_r = fmaxf(fmaxf(redMax[0][rw], redMax[1][rw]),
                        fmaxf(redMax[2][rw], redMax[3][rw])) - 1.0f;
    if (cnt <= CAP) {
      float cv[8];
#pragma unroll
      for (int e = 0; e < 8; ++e) {
        const int ii = lc16 + e * 16;
        cv[e] = (ii < cnt) ? valS[rw][ii] : -1e30f;
      }
      int prevc = -1;
      for (int it = 0; it < 64; ++it) {
        float s = 0.f, c = 0.f;
#pragma unroll
        for (int e = 0; e < 8; ++e) {
          const float v = cv[e];
          if (v > tau_r) { s += v; c += 1.f; }
        }
#pragma unroll
        for (int m = 1; m < 16; m <<= 1) {
          s += __shfl_xor(s, m);
          c += __shfl_xor(c, m);
        }
        tau_r = (s - 1.f) / c;
        const int ci = (int)c;
        if (ci == prevc) break;
        prevc = ci;
      }
    }
    if (lc16 == 0) tauS[rw] = tau_r;   // same-wave LDS RAW: ordered within wave
  }

  // ---- E: avg scatter + sparse PV for this wave's 4 rows ----
  float apv[4] = {0.f, 0.f, 0.f, 0.f};
#pragma unroll
  for (int rr = 0; rr < 4; ++rr) {
    const int r = w * 4 + rr;
    const int cnt = cntS[r];
    if (cnt > CAP) continue;                   // fallback handles
    const float tau_r = tauS[r];
    float* avgRow = avg + ((size_t)b * TS + q0 + r) * TS;
    for (int e = lane; e < cnt; e += 64) {
      const float p = valS[r][e] - tau_r;
      if (p > 0.f) atomicAdd(avgRow + idxS[r][e], p * 0.125f);
    }
    float a = 0.f;
    for (int e = 0; e < cnt; ++e) {
      const float p = valS[r][e] - tau_r;      // LDS broadcast
      if (p > 0.f) a += p * Vb[(size_t)idxS[r][e] * TDH + lane];
    }
    apv[rr] = a;
  }

  // ---- F: dense fallback for overflowed rows (rare; fully general) ----
  __syncthreads();                              // normal rows done with valS/idxS
  float* zrow = &valS[0][0];                    // 16*CAP = 2048 floats, reuse
  float (*hpart)[64] = (float(*)[64])&idxS[0][0];
  for (int r = 0; r < 16; ++r) {
    if (cntS[r] <= CAP) continue;               // uniform branch
    // scatter row r's z into zrow
    if (g == (r >> 2)) {
      const int ir = r & 3;
#pragma unroll
      for (int t = 0; t < 32; ++t) zrow[wcol0 + t * 16 + lc16] = acc[t][ir];
    }
    __syncthreads();
    // dense Michelot over zrow, 256 threads x 8 values
    float lmax = -1e30f;
#pragma unroll
    for (int jj = 0; jj < 8; ++jj) lmax = fmaxf(lmax, zrow[(jj << 8) + tid]);
    for (int off = 32; off; off >>= 1) lmax = fmaxf(lmax, __shfl_down(lmax, off));
    if (lane == 0) redMx[w] = lmax;
    __syncthreads();
    float tau = fmaxf(fmaxf(redMx[0], redMx[1]), fmaxf(redMx[2], redMx[3])) - 1.0f;
    int prevc = -1;
    for (int it = 0; it < 64; ++it) {
      float ls = 0.f, lc = 0.f;
#pragma unroll
      for (int jj = 0; jj < 8; ++jj) {
        const float v = zrow[(jj << 8) + tid];
        if (v > tau) { ls += v; lc += 1.f; }
      }
      for (int off = 32; off; off >>= 1) {
        ls += __shfl_down(ls, off);
        lc += __shfl_down(lc, off);
      }
      if (lane == 0) { redA[w] = ls; redB[w] = lc; }
      __syncthreads();
      const float ts = redA[0] + redA[1] + redA[2] + redA[3];
      const float tc = redB[0] + redB[1] + redB[2] + redB[3];
      tau = (ts - 1.f) / tc;
      const int ci = (int)tc;
      __syncthreads();
      if (ci == prevc) break;
      prevc = ci;
    }
    // dense avg scatter
    float* avgRow = avg + ((size_t)b * TS + q0 + r) * TS;
#pragma unroll
    for (int jj = 0; jj < 8; ++jj) {
      const int j = (jj << 8) + tid;
      const float p = zrow[j] - tau;
      if (p > 0.f) atomicAdd(avgRow + j, p * 0.125f);
    }
    // dense PV: wave w covers its 512 cols, lane = dh
    float a = 0.f;
    for (int j = 0; j < 512; ++j) {
      const float p = zrow[wcol0 + j] - tau;
      if (p > 0.f) a += p * Vb[(size_t)(wcol0 + j) * TDH + lane];
    }
    hpart[w][lane] = a;
    __syncthreads();
    if (w == 0)
      heads[((size_t)b * TS + q0 + r) * TD + h * TDH + lane] =
          (hpart[0][lane] + hpart[1][lane]) + (hpart[2][lane] + hpart[3][lane]);
    __syncthreads();                            // zrow/hpart reused next r
  }

  // ---- write heads for normal rows ----
#pragma unroll
  for (int rr = 0; rr < 4; ++rr) {
    const int r = w * 4 + rr;
    if (cntS[r] <= CAP)
      heads[((size_t)b * TS + q0 + r) * TD + h * TDH + lane] = apv[rr];
  }
}

// ---------------------------------------------------------------------------
extern "C" void kernel_launch(void* const* d_in, const int* in_sizes, int n_in,
                              void* d_out, int out_size, void* d_ws, size_t ws_size,
                              hipStream_t stream) {
  (void)in_sizes; (void)n_in; (void)out_size; (void)ws_size;

  const float* x    = (const float*)d_in[0];
  const float* Wq   = (const float*)d_in[1];
  const float* bq   = (const float*)d_in[2];
  const float* Wk   = (const float*)d_in[3];
  const float* bk   = (const float*)d_in[4];
  const float* Wv   = (const float*)d_in[5];
  const float* bv   = (const float*)d_in[6];
  const float* Wout = (const float*)d_in[7];
  const float* bout = (const float*)d_in[8];

  float* out   = (float*)d_out;
  float* x_out = out;                       // [2,2048,512]
  float* avg   = out + 2097152;             // [2,2048,2048]

  float* ws = (float*)d_ws;
  float* Vb = ws;                           // f32 [2][2048][64]
  float* Hd = ws + 262144;                  // f32 [4096][512]
  short* Qh = (short*)(ws + 2359296);       // bf16 [16][2048][64]
  short* Kh = (short*)(ws + 3407872);       // bf16 [16][2048][64]

  const dim3 blk(256);
  const int BS = 2 * TS;

  gemm_bias<<<dim3(BS / 64, TD / 64), blk, 0, stream>>>(x, Wq, bq, nullptr, Qh, 1, BS, TD, TD);
  gemm_bias<<<dim3(BS / 64, TD / 64), blk, 0, stream>>>(x, Wk, bk, nullptr, Kh, 1, BS, TD, TD);
  gemm_bias<<<dim3(BS / 64, TDH / 64), blk, 0, stream>>>(x, Wv, bv, Vb, nullptr, 0, BS, TDH, TD);

  hipMemsetAsync(avg, 0, (size_t)2 * TS * TS * sizeof(float), stream);

  fused_attn<<<dim3(TS / 16, 16), blk, 0, stream>>>(Qh, Kh, Vb, Hd, avg);

  gemm_bias<<<dim3(BS / 64, TD / 64), blk, 0, stream>>>(Hd, Wout, bout, x_out, nullptr, 0, BS, TD, TD);
}